// Round 16
// baseline (446.948 us; speedup 1.0000x reference)
//
#include <hip/hip_runtime.h>
#include <hip/hip_bf16.h>

#define ALPHA 0.05f
#define SLOPE 0.2f
#define LCAP 64

typedef __attribute__((ext_vector_type(8))) short short8v;
typedef __attribute__((ext_vector_type(8))) unsigned short ushort8v;
typedef __attribute__((ext_vector_type(4))) float floatx4;

__device__ inline ushort f2b(float f) {
    uint u = __float_as_uint(f);
    return (ushort)((u + 0x7fffu + ((u >> 16) & 1u)) >> 16);
}
__device__ inline float b2f(ushort b) { return __uint_as_float(((uint)b) << 16); }

// async global->LDS, 16B per lane (dest = wave-uniform base + lane*16)
__device__ inline void gload_lds16(const ushort* g, ushort* l) {
    __builtin_amdgcn_global_load_lds(
        (const __attribute__((address_space(1))) uint*)g,
        (__attribute__((address_space(3))) uint*)l, 16, 0, 0);
}

// ---------------- CSR build ----------------

__global__ void hist_kernel(const int* __restrict__ dst, int* __restrict__ counts, int E) {
    int e = blockIdx.x * blockDim.x + threadIdx.x;
    if (e < E) atomicAdd(&counts[dst[e]], 1);
}

__global__ __launch_bounds__(256) void scan_part(const int* __restrict__ counts,
                                                 int* __restrict__ offsets,
                                                 int* __restrict__ partial, int n) {
    __shared__ int sd[256];
    int i = blockIdx.x * 256 + threadIdx.x;
    int v = (i < n) ? counts[i] : 0;
    sd[threadIdx.x] = v;
    __syncthreads();
    for (int off = 1; off < 256; off <<= 1) {
        int t = (threadIdx.x >= off) ? sd[threadIdx.x - off] : 0;
        __syncthreads();
        sd[threadIdx.x] += t;
        __syncthreads();
    }
    if (i < n) offsets[i + 1] = sd[threadIdx.x];
    if (threadIdx.x == 255) partial[blockIdx.x] = sd[255];
}

__global__ __launch_bounds__(256) void scan_top(int* __restrict__ partial, int nb) {
    __shared__ int sd[256];
    int v = (threadIdx.x < nb) ? partial[threadIdx.x] : 0;
    sd[threadIdx.x] = v;
    __syncthreads();
    for (int off = 1; off < 256; off <<= 1) {
        int t = (threadIdx.x >= off) ? sd[threadIdx.x - off] : 0;
        __syncthreads();
        sd[threadIdx.x] += t;
        __syncthreads();
    }
    if (threadIdx.x < nb) partial[threadIdx.x] = sd[threadIdx.x];
}

__global__ __launch_bounds__(256) void scan_add(int* __restrict__ offsets,
                                                int* __restrict__ cursor,
                                                const int* __restrict__ partial, int n) {
    int i = blockIdx.x * 256 + threadIdx.x;
    if (i >= n) return;
    int add = (blockIdx.x > 0) ? partial[blockIdx.x - 1] : 0;
    int v = offsets[i + 1] + add;
    offsets[i + 1] = v;
    if (i + 1 < n) cursor[i + 1] = v;
    if (i == 0) { offsets[0] = 0; cursor[0] = 0; }
}

// pack (src<<3)|etype into one int per edge
__global__ void scatter_kernel(const int* __restrict__ src, const int* __restrict__ dst,
                               const int* __restrict__ et, int* __restrict__ cursor,
                               int* __restrict__ se, int E) {
    int e = blockIdx.x * blockDim.x + threadIdx.x;
    if (e >= E) return;
    int d = dst[e];
    int pos = atomicAdd(&cursor[d], 1);
    se[pos] = (src[e] << 3) | et[e];
}

// ---------------- weight prep (GAT + FC + layer-2 weights, one dispatch) ----------------

__global__ void wprep(const float* __restrict__ W0f, const float* __restrict__ W1f,
                      const float* __restrict__ WRf,
                      const float* __restrict__ fw0, const float* __restrict__ fw1,
                      const float* __restrict__ fw2,
                      const float* __restrict__ W2f, const float* __restrict__ WR2f,
                      ushort* __restrict__ Wt0, ushort* __restrict__ Wt1,
                      ushort* __restrict__ WtR,
                      ushort* __restrict__ ft0, ushort* __restrict__ ft1,
                      ushort* __restrict__ ft2, ushort* __restrict__ Wt2R) {
    int i = blockIdx.x * blockDim.x + threadIdx.x;
    if (i < 16384) {                                  // W0 [64][256] -> Wt0 [256][64]
        int k = i / 256, n = i % 256;
        Wt0[n * 64 + k] = f2b(W0f[i]);
    } else if (i < 16384 + 65536) {                   // W1 [256][256] -> Wt1
        int j = i - 16384;
        int k = j / 256, n = j % 256;
        Wt1[n * 256 + k] = f2b(W1f[j]);
    } else if (i < 16384 + 2 * 65536) {               // resW1 -> WtR
        int j = i - 16384 - 65536;
        int k = j / 256, n = j % 256;
        WtR[n * 256 + k] = f2b(WRf[j]);
    } else if (i < 147456 + 8192) {                   // fcw0 [128][64] -> ft0 [64][128]
        int j = i - 147456;
        int k = j / 64, n = j % 64;
        ft0[n * 128 + k] = f2b(fw0[j]);
    } else if (i < 147456 + 8192 + 16384) {           // fcw1 [256][64] -> ft1 [64][256]
        int j = i - 147456 - 8192;
        int k = j / 64, n = j % 64;
        ft1[n * 256 + k] = f2b(fw1[j]);
    } else if (i < 147456 + 8192 + 16384 + 4096) {    // fcw2 [64][64] -> ft2 [64][64]
        int j = i - 147456 - 8192 - 16384;
        int k = j / 64, n = j % 64;
        ft2[n * 64 + k] = f2b(fw2[j]);
    } else if (i < 176128 + 4096) {                   // W2 [256][16] -> Wt2R rows 0-15
        int j = i - 176128;
        int k = j / 16, n = j % 16;
        Wt2R[n * 256 + k] = f2b(W2f[j]);
    } else if (i < 176128 + 8192) {                   // resW2 [256][16] -> Wt2R rows 16-31
        int j = i - 176128 - 4096;
        int k = j / 16, n = j % 16;
        Wt2R[(16 + n) * 256 + k] = f2b(WR2f[j]);
    }
}

// ---------------- merged etype attention (3 layers, one dispatch) ----------------

__global__ __launch_bounds__(512) void etype_all(
    const float* __restrict__ eemb0, const float* __restrict__ We0, const float* __restrict__ ae0, float* __restrict__ out0,
    const float* __restrict__ eemb1, const float* __restrict__ We1, const float* __restrict__ ae1, float* __restrict__ out1,
    const float* __restrict__ eemb2, const float* __restrict__ We2, const float* __restrict__ ae2, float* __restrict__ out2) {
    int layer = blockIdx.x / 6, t = blockIdx.x % 6;
    const float *eemb, *We, *ae;
    float* out;
    int H;
    if (layer == 0)      { eemb = eemb0; We = We0; ae = ae0; out = out0; H = 8; }
    else if (layer == 1) { eemb = eemb1; We = We1; ae = ae1; out = out1; H = 8; }
    else                 { eemb = eemb2; We = We2; ae = ae2; out = out2; H = 1; }
    __shared__ float es[64];
    int j = threadIdx.x;
    if (j < 64) es[j] = eemb[t * 64 + j];
    __syncthreads();
    if (j >= H * 64) return;
    float wsum = 0.f;
#pragma unroll 8
    for (int k = 0; k < 64; ++k) wsum += es[k] * We[k * (H * 64) + j];
    float v = wsum * ae[j];
#pragma unroll
    for (int off = 32; off > 0; off >>= 1) v += __shfl_down(v, off, 64);
    if ((j & 63) == 0) out[t * H + (j >> 6)] = v;
}

// ---------------- bf16 MFMA GEMM (global_load_lds) + optional el/er epilogue ----------------

template<bool ATTN>
__global__ __launch_bounds__(256) void gemm_bf16(const ushort* __restrict__ A,
                                                 const ushort* __restrict__ Bt,
                                                 ushort* __restrict__ Cb,
                                                 const float* __restrict__ al,
                                                 const float* __restrict__ ar,
                                                 float* __restrict__ el,
                                                 float* __restrict__ er,
                                                 int M, int N, int K) {
    __shared__ ushort As[128 * 32];
    __shared__ ushort Bs[128 * 32];
    int bm = blockIdx.y * 128, bn = blockIdx.x * 128;
    int tid = threadIdx.x;
    int wave = tid >> 6, lane = tid & 63;
    int wm = (wave >> 1) * 64, wn = (wave & 1) * 64;
    int r = tid >> 2, c = (tid & 3) * 8;
    floatx4 acc[4][4] = {};
    for (int k0 = 0; k0 < K; k0 += 32) {
        gload_lds16(&A[(long)(bm + r) * K + k0 + c],       &As[(size_t)tid * 8]);
        gload_lds16(&A[(long)(bm + 64 + r) * K + k0 + c],  &As[(size_t)(256 + tid) * 8]);
        gload_lds16(&Bt[(long)(bn + r) * K + k0 + c],      &Bs[(size_t)tid * 8]);
        gload_lds16(&Bt[(long)(bn + 64 + r) * K + k0 + c], &Bs[(size_t)(256 + tid) * 8]);
        __syncthreads();
        int lr = lane & 15, lk = (lane >> 4) * 8;
        short8v af[4], bfr[4];
#pragma unroll
        for (int i = 0; i < 4; ++i)
            af[i] = *reinterpret_cast<const short8v*>(&As[(wm + i * 16 + lr) * 32 + lk]);
#pragma unroll
        for (int j = 0; j < 4; ++j)
            bfr[j] = *reinterpret_cast<const short8v*>(&Bs[(wn + j * 16 + lr) * 32 + lk]);
#pragma unroll
        for (int i = 0; i < 4; ++i)
#pragma unroll
            for (int j = 0; j < 4; ++j)
                acc[i][j] = __builtin_amdgcn_mfma_f32_16x16x32_bf16(af[i], bfr[j], acc[i][j], 0, 0, 0);
        __syncthreads();
    }
    int col = lane & 15, rbase = (lane >> 4) * 4;
#pragma unroll
    for (int i = 0; i < 4; ++i) {
#pragma unroll
        for (int rr = 0; rr < 4; ++rr) {
            int gm = bm + wm + i * 16 + rbase + rr;
            if (gm >= M) continue;
#pragma unroll
            for (int j = 0; j < 4; ++j) {
                int gn = bn + wn + j * 16 + col;
                Cb[(long)gm * N + gn] = f2b(acc[i][j][rr]);
            }
        }
    }
    if (ATTN) {
        int hA = (bn + wn) >> 5;
        float alv[4], arv[4];
#pragma unroll
        for (int j = 0; j < 4; ++j) {
            int h = hA + (j >> 1);
            int o = (j & 1) * 16 + col;
            alv[j] = al[h * 32 + o];
            arv[j] = ar[h * 32 + o];
        }
#pragma unroll
        for (int i = 0; i < 4; ++i) {
#pragma unroll
            for (int rr = 0; rr < 4; ++rr) {
                float slA = acc[i][0][rr] * alv[0] + acc[i][1][rr] * alv[1];
                float slB = acc[i][2][rr] * alv[2] + acc[i][3][rr] * alv[3];
                float srA = acc[i][0][rr] * arv[0] + acc[i][1][rr] * arv[1];
                float srB = acc[i][2][rr] * arv[2] + acc[i][3][rr] * arv[3];
#pragma unroll
                for (int off = 1; off < 16; off <<= 1) {
                    slA += __shfl_xor(slA, off, 64);
                    slB += __shfl_xor(slB, off, 64);
                    srA += __shfl_xor(srA, off, 64);
                    srB += __shfl_xor(srB, off, 64);
                }
                int gm = bm + wm + i * 16 + rbase + rr;
                if (col == 0 && gm < M) {
                    el[gm * 8 + hA]     = slA;
                    el[gm * 8 + hA + 1] = slB;
                    er[gm * 8 + hA]     = srA;
                    er[gm * 8 + hA + 1] = srB;
                }
            }
        }
    }
}

// ---------------- dual-B GEMM: C1 = A@B1^T (+el/er), C2 = A@B2^T ----------------

__global__ __launch_bounds__(256) void gemm_dual(const ushort* __restrict__ A,
                                                 const ushort* __restrict__ B1,
                                                 const ushort* __restrict__ B2,
                                                 ushort* __restrict__ C1,
                                                 ushort* __restrict__ C2,
                                                 const float* __restrict__ al,
                                                 const float* __restrict__ ar,
                                                 float* __restrict__ el,
                                                 float* __restrict__ er,
                                                 int M, int N, int K) {
    __shared__ ushort As[128 * 32];
    __shared__ ushort Bs1[128 * 32];
    __shared__ ushort Bs2[128 * 32];
    int bm = blockIdx.y * 128, bn = blockIdx.x * 128;
    int tid = threadIdx.x;
    int wave = tid >> 6, lane = tid & 63;
    int wm = (wave >> 1) * 64, wn = (wave & 1) * 64;
    int r = tid >> 2, c = (tid & 3) * 8;
    floatx4 acc1[4][4] = {};
    floatx4 acc2[4][4] = {};
    for (int k0 = 0; k0 < K; k0 += 32) {
        gload_lds16(&A[(long)(bm + r) * K + k0 + c],        &As[(size_t)tid * 8]);
        gload_lds16(&A[(long)(bm + 64 + r) * K + k0 + c],   &As[(size_t)(256 + tid) * 8]);
        gload_lds16(&B1[(long)(bn + r) * K + k0 + c],       &Bs1[(size_t)tid * 8]);
        gload_lds16(&B1[(long)(bn + 64 + r) * K + k0 + c],  &Bs1[(size_t)(256 + tid) * 8]);
        gload_lds16(&B2[(long)(bn + r) * K + k0 + c],       &Bs2[(size_t)tid * 8]);
        gload_lds16(&B2[(long)(bn + 64 + r) * K + k0 + c],  &Bs2[(size_t)(256 + tid) * 8]);
        __syncthreads();
        int lr = lane & 15, lk = (lane >> 4) * 8;
        short8v af[4], bfr[4];
#pragma unroll
        for (int i = 0; i < 4; ++i)
            af[i] = *reinterpret_cast<const short8v*>(&As[(wm + i * 16 + lr) * 32 + lk]);
#pragma unroll
        for (int j = 0; j < 4; ++j)
            bfr[j] = *reinterpret_cast<const short8v*>(&Bs1[(wn + j * 16 + lr) * 32 + lk]);
#pragma unroll
        for (int i = 0; i < 4; ++i)
#pragma unroll
            for (int j = 0; j < 4; ++j)
                acc1[i][j] = __builtin_amdgcn_mfma_f32_16x16x32_bf16(af[i], bfr[j], acc1[i][j], 0, 0, 0);
#pragma unroll
        for (int j = 0; j < 4; ++j)
            bfr[j] = *reinterpret_cast<const short8v*>(&Bs2[(wn + j * 16 + lr) * 32 + lk]);
#pragma unroll
        for (int i = 0; i < 4; ++i)
#pragma unroll
            for (int j = 0; j < 4; ++j)
                acc2[i][j] = __builtin_amdgcn_mfma_f32_16x16x32_bf16(af[i], bfr[j], acc2[i][j], 0, 0, 0);
        __syncthreads();
    }
    int col = lane & 15, rbase = (lane >> 4) * 4;
#pragma unroll
    for (int i = 0; i < 4; ++i) {
#pragma unroll
        for (int rr = 0; rr < 4; ++rr) {
            int gm = bm + wm + i * 16 + rbase + rr;
            if (gm >= M) continue;
#pragma unroll
            for (int j = 0; j < 4; ++j) {
                int gn = bn + wn + j * 16 + col;
                C1[(long)gm * N + gn] = f2b(acc1[i][j][rr]);
                C2[(long)gm * N + gn] = f2b(acc2[i][j][rr]);
            }
        }
    }
    int hA = (bn + wn) >> 5;
    float alv[4], arv[4];
#pragma unroll
    for (int j = 0; j < 4; ++j) {
        int h = hA + (j >> 1);
        int o = (j & 1) * 16 + col;
        alv[j] = al[h * 32 + o];
        arv[j] = ar[h * 32 + o];
    }
#pragma unroll
    for (int i = 0; i < 4; ++i) {
#pragma unroll
        for (int rr = 0; rr < 4; ++rr) {
            float slA = acc1[i][0][rr] * alv[0] + acc1[i][1][rr] * alv[1];
            float slB = acc1[i][2][rr] * alv[2] + acc1[i][3][rr] * alv[3];
            float srA = acc1[i][0][rr] * arv[0] + acc1[i][1][rr] * arv[1];
            float srB = acc1[i][2][rr] * arv[2] + acc1[i][3][rr] * arv[3];
#pragma unroll
            for (int off = 1; off < 16; off <<= 1) {
                slA += __shfl_xor(slA, off, 64);
                slB += __shfl_xor(slB, off, 64);
                srA += __shfl_xor(srA, off, 64);
                srB += __shfl_xor(srB, off, 64);
            }
            int gm = bm + wm + i * 16 + rbase + rr;
            if (col == 0 && gm < M) {
                el[gm * 8 + hA]     = slA;
                el[gm * 8 + hA + 1] = slB;
                er[gm * 8 + hA]     = srA;
                er[gm * 8 + hA + 1] = srB;
            }
        }
    }
}

// ---------------- input FC: f32 A reg-staged->bf16 LDS, B via gload_lds, bias epilogue ----------------

__global__ __launch_bounds__(256) void gemm_fc(const float* __restrict__ x0,
                                               const float* __restrict__ x1,
                                               const float* __restrict__ x2,
                                               const ushort* __restrict__ ft0,
                                               const ushort* __restrict__ ft1,
                                               const ushort* __restrict__ ft2,
                                               const float* __restrict__ b0,
                                               const float* __restrict__ b1,
                                               const float* __restrict__ b2,
                                               ushort* __restrict__ C,
                                               int n0, int n1, int n2) {
    int z = blockIdx.z;
    const float* A;
    const ushort* Bt;
    const float* bias;
    int M, K;
    long coff;
    if (z == 0)      { A = x0; Bt = ft0; bias = b0; M = n0; K = 128; coff = 0; }
    else if (z == 1) { A = x1; Bt = ft1; bias = b1; M = n1; K = 256; coff = (long)n0 * 64; }
    else             { A = x2; Bt = ft2; bias = b2; M = n2; K = 64;  coff = (long)(n0 + n1) * 64; }
    int bm = blockIdx.y * 128;
    if (bm >= M) return;
    __shared__ ushort As[128 * 32];
    __shared__ ushort Bs[64 * 32];
    int tid = threadIdx.x;
    int wave = tid >> 6, lane = tid & 63;
    int wm = (wave >> 1) * 64, wn = (wave & 1) * 32;
    int r = tid >> 2, c = (tid & 3) * 8;
    floatx4 acc[4][2] = {};
    for (int k0 = 0; k0 < K; k0 += 32) {
        {
            int gm0 = bm + r, gm1 = bm + 64 + r;
            ushort8v u0 = {0, 0, 0, 0, 0, 0, 0, 0};
            ushort8v u1 = {0, 0, 0, 0, 0, 0, 0, 0};
            if (gm0 < M) {
                float4 lo = *reinterpret_cast<const float4*>(&A[(long)gm0 * K + k0 + c]);
                float4 hi = *reinterpret_cast<const float4*>(&A[(long)gm0 * K + k0 + c + 4]);
                u0[0] = f2b(lo.x); u0[1] = f2b(lo.y); u0[2] = f2b(lo.z); u0[3] = f2b(lo.w);
                u0[4] = f2b(hi.x); u0[5] = f2b(hi.y); u0[6] = f2b(hi.z); u0[7] = f2b(hi.w);
            }
            if (gm1 < M) {
                float4 lo = *reinterpret_cast<const float4*>(&A[(long)gm1 * K + k0 + c]);
                float4 hi = *reinterpret_cast<const float4*>(&A[(long)gm1 * K + k0 + c + 4]);
                u1[0] = f2b(lo.x); u1[1] = f2b(lo.y); u1[2] = f2b(lo.z); u1[3] = f2b(lo.w);
                u1[4] = f2b(hi.x); u1[5] = f2b(hi.y); u1[6] = f2b(hi.z); u1[7] = f2b(hi.w);
            }
            *reinterpret_cast<ushort8v*>(&As[(size_t)tid * 8]) = u0;
            *reinterpret_cast<ushort8v*>(&As[(size_t)(256 + tid) * 8]) = u1;
        }
        gload_lds16(&Bt[(long)r * K + k0 + c], &Bs[(size_t)tid * 8]);
        __syncthreads();
        int lr = lane & 15, lk = (lane >> 4) * 8;
        short8v af[4], bfr[2];
#pragma unroll
        for (int i = 0; i < 4; ++i)
            af[i] = *reinterpret_cast<const short8v*>(&As[(wm + i * 16 + lr) * 32 + lk]);
#pragma unroll
        for (int j = 0; j < 2; ++j)
            bfr[j] = *reinterpret_cast<const short8v*>(&Bs[(wn + j * 16 + lr) * 32 + lk]);
#pragma unroll
        for (int i = 0; i < 4; ++i)
#pragma unroll
            for (int j = 0; j < 2; ++j)
                acc[i][j] = __builtin_amdgcn_mfma_f32_16x16x32_bf16(af[i], bfr[j], acc[i][j], 0, 0, 0);
        __syncthreads();
    }
    int col = lane & 15, rbase = (lane >> 4) * 4;
#pragma unroll
    for (int i = 0; i < 4; ++i) {
#pragma unroll
        for (int rr = 0; rr < 4; ++rr) {
            int gm = bm + wm + i * 16 + rbase + rr;
            if (gm >= M) continue;
#pragma unroll
            for (int j = 0; j < 2; ++j) {
                int gn = wn + j * 16 + col;
                C[coff + (long)gm * 64 + gn] = f2b(acc[i][j][rr] + bias[gn]);
            }
        }
    }
}

// ---------------- layer-2 MFMA: s1=A@W2 (->feat2b,el,er), s2=A@resW2 (->resout) ----------------

__global__ __launch_bounds__(256) void gemm_small(const ushort* __restrict__ A,
                                                  const ushort* __restrict__ Wt2R,
                                                  ushort* __restrict__ feat2b,
                                                  float* __restrict__ resout,
                                                  const float* __restrict__ al,
                                                  const float* __restrict__ ar,
                                                  float* __restrict__ el,
                                                  float* __restrict__ er, int M) {
    __shared__ ushort As[128 * 32];
    __shared__ ushort Bs[32 * 256];
    int tid = threadIdx.x;
    int wave = tid >> 6, lane = tid & 63;
    int bm = blockIdx.x * 128;
    for (int i = tid; i < 32 * 256 / 8; i += 256)
        *reinterpret_cast<ushort8v*>(&Bs[(size_t)i * 8]) =
            *reinterpret_cast<const ushort8v*>(&Wt2R[(size_t)i * 8]);
    __syncthreads();
    int r = tid >> 2, c = (tid & 3) * 8;
    floatx4 acc[2][2] = {};
    for (int k0 = 0; k0 < 256; k0 += 32) {
        gload_lds16(&A[(long)(bm + r) * 256 + k0 + c],      &As[(size_t)tid * 8]);
        gload_lds16(&A[(long)(bm + 64 + r) * 256 + k0 + c], &As[(size_t)(256 + tid) * 8]);
        __syncthreads();
        int lr = lane & 15, lk = (lane >> 4) * 8;
        short8v af[2], bfr[2];
#pragma unroll
        for (int i = 0; i < 2; ++i)
            af[i] = *reinterpret_cast<const short8v*>(&As[(wave * 32 + i * 16 + lr) * 32 + lk]);
#pragma unroll
        for (int j = 0; j < 2; ++j)
            bfr[j] = *reinterpret_cast<const short8v*>(&Bs[(j * 16 + lr) * 256 + k0 + lk]);
#pragma unroll
        for (int i = 0; i < 2; ++i)
#pragma unroll
            for (int j = 0; j < 2; ++j)
                acc[i][j] = __builtin_amdgcn_mfma_f32_16x16x32_bf16(af[i], bfr[j], acc[i][j], 0, 0, 0);
        __syncthreads();
    }
    int col = lane & 15, rbase = (lane >> 4) * 4;
    float alv = al[col], arv = ar[col];
#pragma unroll
    for (int i = 0; i < 2; ++i) {
#pragma unroll
        for (int rr = 0; rr < 4; ++rr) {
            int gm = bm + wave * 32 + i * 16 + rbase + rr;
            float s1 = acc[i][0][rr];
            float s2 = acc[i][1][rr];
            float sl = s1 * alv, sr = s1 * arv;
#pragma unroll
            for (int off = 1; off < 16; off <<= 1) {
                sl += __shfl_xor(sl, off, 64);
                sr += __shfl_xor(sr, off, 64);
            }
            if (gm < M) {
                feat2b[(long)gm * 16 + col] = f2b(s1);
                resout[(long)gm * 16 + col] = s2;
                if (col == 0) { el[gm] = sl; er[gm] = sr; }
            }
        }
    }
}

// ---------------- fused logits+softmax+aggregate, H=8, OUT=32, bf16 feat ----------------
// one block (64 threads = 1 wave) per dst node; LDS-staged gather via global_load_lds:
// batches of 8 edge rows (4KB) double-buffered; counted vmcnt keeps 1-2 batches in flight.

template<bool BLEND, bool SAVE, bool RES>
__global__ __launch_bounds__(64) void fused_edge_h8(
    const int* __restrict__ offsets, const int* __restrict__ se,
    const float* __restrict__ el, const float* __restrict__ er,
    const float* __restrict__ etatt,
    const ushort* __restrict__ featb,
    const ushort* __restrict__ a0_in, ushort* __restrict__ a0_out,
    const ushort* __restrict__ resin, ushort* __restrict__ outb, int N) {
    int d = blockIdx.x;
    int lane = threadIdx.x;
    int lo = offsets[d], hi = offsets[d + 1];
    int deg = hi - lo;
    __shared__ float a_lds[LCAP][8];
    __shared__ int   s_lds[LCAP];
    __shared__ float er_s[8];
    __shared__ float m_s[8], inv_s[8];
    __shared__ ushort stage[2][2048];   // 2 x 8 edge rows x 512B
    if (lane < 8) er_s[lane] = er[d * 8 + lane];
    __syncthreads();
    bool fast = (deg <= LCAP);
    int half = lane >> 5, t = lane & 31;
    int h8 = t >> 2;
    if (fast) {
        for (int i = lane; i < deg * 8; i += 64) {
            int p = i >> 3, h = i & 7;
            int v0 = se[lo + p];
            int s = v0 >> 3, tt = v0 & 7;
            if (h == 0) s_lds[p] = s;
            float v = el[s * 8 + h] + er_s[h] + etatt[tt * 8 + h];
            a_lds[p][h] = v > 0.f ? v : SLOPE * v;
        }
        __syncthreads();
        {
            int g = lane >> 3, h = lane & 7;
            float m = -INFINITY;
            for (int p = g; p < deg; p += 8) m = fmaxf(m, a_lds[p][h]);
#pragma unroll
            for (int off = 8; off < 64; off <<= 1) m = fmaxf(m, __shfl_xor(m, off, 64));
            float ssum = 0.f;
            for (int p = g; p < deg; p += 8) ssum += __expf(a_lds[p][h] - m);
#pragma unroll
            for (int off = 8; off < 64; off <<= 1) ssum += __shfl_xor(ssum, off, 64);
            if (g == 0) {
                m_s[h] = m;
                inv_s[h] = ssum > 0.f ? 1.f / ssum : 0.f;
            }
        }
        __syncthreads();
        for (int i = lane; i < deg * 8; i += 64) {
            int p = i >> 3, h = i & 7;
            float a = __expf(a_lds[p][h] - m_s[h]) * inv_s[h];
            if (BLEND) a = a * (1.f - ALPHA) + b2f(a0_in[lo * 8 + i]) * ALPHA;
            a_lds[p][h] = a;
            if (SAVE) a0_out[lo * 8 + i] = f2b(a);
        }
        __syncthreads();
    } else {
        int g = lane >> 3, h = lane & 7;
        float m = -INFINITY;
        for (int p = g; p < deg; p += 8) {
            int v0 = se[lo + p];
            int s = v0 >> 3, tt = v0 & 7;
            float v = el[s * 8 + h] + er_s[h] + etatt[tt * 8 + h];
            v = v > 0.f ? v : SLOPE * v;
            m = fmaxf(m, v);
        }
#pragma unroll
        for (int off = 8; off < 64; off <<= 1) m = fmaxf(m, __shfl_xor(m, off, 64));
        float ssum = 0.f;
        for (int p = g; p < deg; p += 8) {
            int v0 = se[lo + p];
            int s = v0 >> 3, tt = v0 & 7;
            float v = el[s * 8 + h] + er_s[h] + etatt[tt * 8 + h];
            v = v > 0.f ? v : SLOPE * v;
            ssum += __expf(v - m);
        }
#pragma unroll
        for (int off = 8; off < 64; off <<= 1) ssum += __shfl_xor(ssum, off, 64);
        if (g == 0) {
            m_s[h] = m;
            inv_s[h] = ssum > 0.f ? 1.f / ssum : 0.f;
        }
        __syncthreads();
        if (SAVE) {
            for (int i = lane; i < deg * 8; i += 64) {
                int p = i >> 3, hh = i & 7;
                int v0 = se[lo + p];
                int s = v0 >> 3, tt = v0 & 7;
                float v = el[s * 8 + hh] + er_s[hh] + etatt[tt * 8 + hh];
                v = v > 0.f ? v : SLOPE * v;
                float a = __expf(v - m_s[hh]) * inv_s[hh];
                if (BLEND) a = a * (1.f - ALPHA) + b2f(a0_in[lo * 8 + i]) * ALPHA;
                a0_out[lo * 8 + i] = f2b(a);
            }
        }
    }
    // aggregation
    float acc[8];
#pragma unroll
    for (int k = 0; k < 8; ++k) acc[k] = 0.f;
    if (RES && half == 0) {
        uint4 rv = *reinterpret_cast<const uint4*>(&resin[(long)d * 256 + t * 8]);
        const uint* rp = reinterpret_cast<const uint*>(&rv);
#pragma unroll
        for (int q = 0; q < 4; ++q) {
            acc[2 * q]     = __uint_as_float(rp[q] << 16);
            acc[2 * q + 1] = __uint_as_float(rp[q] & 0xffff0000u);
        }
    }
    if (fast) {
        // issue one batch (4 gload instructions = 8 edge rows) into buffer `buf`
        auto issue = [&](int buf, int pb) {
#pragma unroll
            for (int u = 0; u < 4; ++u) {
                int e0 = pb + 2 * u, e1 = pb + 2 * u + 1;
                e0 = e0 < deg ? e0 : deg - 1;
                e1 = e1 < deg ? e1 : deg - 1;
                int srow = (lane < 32) ? s_lds[e0] : s_lds[e1];
                gload_lds16(&featb[(long)srow * 256 + (lane & 31) * 8],
                            &stage[buf][u * 512]);
            }
        };
        issue(0, 0);
        if (deg > 8) issue(1, 8);
        for (int pb = 0; pb < deg; pb += 8) {
            int cur = (pb >> 3) & 1;
            if (pb + 8 < deg) {
                asm volatile("s_waitcnt vmcnt(4)" ::: "memory");
            } else {
                asm volatile("s_waitcnt vmcnt(0)" ::: "memory");
            }
            __builtin_amdgcn_sched_barrier(0);
            // consume: each half-wave handles 4 edges of the batch
#pragma unroll
            for (int u = 0; u < 4; ++u) {
                int j = half * 4 + u;
                if (pb + j < deg) {
                    float a = a_lds[pb + j][h8];
                    uint4 fv = *reinterpret_cast<const uint4*>(&stage[cur][j * 256 + t * 8]);
                    const uint* fp = reinterpret_cast<const uint*>(&fv);
#pragma unroll
                    for (int q = 0; q < 4; ++q) {
                        acc[2 * q]     += __uint_as_float(fp[q] << 16) * a;
                        acc[2 * q + 1] += __uint_as_float(fp[q] & 0xffff0000u) * a;
                    }
                }
            }
            __builtin_amdgcn_sched_barrier(0);
            if (pb + 16 < deg) issue(cur, pb + 16);
        }
    } else {
        for (int p = half; p < deg; p += 2) {
            int v0 = se[lo + p];
            int s = v0 >> 3, tt = v0 & 7;
            float v = el[s * 8 + h8] + er_s[h8] + etatt[tt * 8 + h8];
            v = v > 0.f ? v : SLOPE * v;
            float a = __expf(v - m_s[h8]) * inv_s[h8];
            if (BLEND) a = a * (1.f - ALPHA) + b2f(a0_in[(long)(lo + p) * 8 + h8]) * ALPHA;
            uint4 fv = *reinterpret_cast<const uint4*>(&featb[(long)s * 256 + t * 8]);
            const uint* fp = reinterpret_cast<const uint*>(&fv);
#pragma unroll
            for (int q = 0; q < 4; ++q) {
                uint u = fp[q];
                acc[2 * q]     += __uint_as_float(u << 16) * a;
                acc[2 * q + 1] += __uint_as_float(u & 0xffff0000u) * a;
            }
        }
    }
#pragma unroll
    for (int k = 0; k < 8; ++k) acc[k] += __shfl_down(acc[k], 32);
    if (half == 0) {
        ushort8v o;
#pragma unroll
        for (int k = 0; k < 8; ++k) {
            float v = acc[k];
            v = v > 0.f ? v : __expf(v) - 1.f;
            o[k] = f2b(v);
        }
        *reinterpret_cast<ushort8v*>(&outb[(long)d * 256 + t * 8]) = o;
    }
}

// ---------------- fused edge kernel, H=1, OUT=16, bf16 feat, + residual add ----------------

__global__ __launch_bounds__(64) void fused_edge_h1(
    const int* __restrict__ offsets, const int* __restrict__ se,
    const float* __restrict__ el, const float* __restrict__ er,
    const float* __restrict__ etatt,
    const ushort* __restrict__ featb2, const float* __restrict__ resout,
    float* __restrict__ out, int N) {
    int d = blockIdx.x;
    int lane = threadIdx.x;
    int lo = offsets[d], hi = offsets[d + 1];
    int deg = hi - lo;
    __shared__ float a_lds[512];
    float er_d = er[d];
    bool fast = (deg <= 512);
    float m = -INFINITY, inv = 0.f;
    if (fast) {
        for (int i = lane; i < deg; i += 64) {
            int v0 = se[lo + i];
            int s = v0 >> 3, t = v0 & 7;
            float v = el[s] + er_d + etatt[t];
            a_lds[i] = v > 0.f ? v : SLOPE * v;
        }
        __syncthreads();
        for (int i = lane; i < deg; i += 64) m = fmaxf(m, a_lds[i]);
#pragma unroll
        for (int off = 1; off < 64; off <<= 1) m = fmaxf(m, __shfl_xor(m, off, 64));
        float ssum = 0.f;
        for (int i = lane; i < deg; i += 64) ssum += __expf(a_lds[i] - m);
#pragma unroll
        for (int off = 1; off < 64; off <<= 1) ssum += __shfl_xor(ssum, off, 64);
        inv = ssum > 0.f ? 1.f / ssum : 0.f;
        for (int i = lane; i < deg; i += 64) a_lds[i] = __expf(a_lds[i] - m) * inv;
        __syncthreads();
    } else {
        for (int i = lane; i < deg; i += 64) {
            int v0 = se[lo + i];
            int s = v0 >> 3, t = v0 & 7;
            float v = el[s] + er_d + etatt[t];
            v = v > 0.f ? v : SLOPE * v;
            m = fmaxf(m, v);
        }
#pragma unroll
        for (int off = 1; off < 64; off <<= 1) m = fmaxf(m, __shfl_xor(m, off, 64));
        float ssum = 0.f;
        for (int i = lane; i < deg; i += 64) {
            int v0 = se[lo + i];
            int s = v0 >> 3, t = v0 & 7;
            float v = el[s] + er_d + etatt[t];
            v = v > 0.f ? v : SLOPE * v;
            ssum += __expf(v - m);
        }
#pragma unroll
        for (int off = 1; off < 64; off <<= 1) ssum += __shfl_xor(ssum, off, 64);
        inv = ssum > 0.f ? 1.f / ssum : 0.f;
    }
    int g = lane >> 1, t = lane & 1;       // 32 edge groups x 2 lanes (8 bf16 ch each)
    float acc[8];
#pragma unroll
    for (int k = 0; k < 8; ++k) acc[k] = 0.f;
    for (int p = g; p < deg; p += 32) {
        int v0 = se[lo + p];
        int s = v0 >> 3;
        float a;
        if (fast) a = a_lds[p];
        else {
            int tt = v0 & 7;
            float v = el[s] + er_d + etatt[tt];
            v = v > 0.f ? v : SLOPE * v;
            a = __expf(v - m) * inv;
        }
        uint4 fv = *reinterpret_cast<const uint4*>(&featb2[(long)s * 16 + t * 8]);
        const uint* fp = reinterpret_cast<const uint*>(&fv);
#pragma unroll
        for (int q = 0; q < 4; ++q) {
            acc[2 * q]     += __uint_as_float(fp[q] << 16) * a;
            acc[2 * q + 1] += __uint_as_float(fp[q] & 0xffff0000u) * a;
        }
    }
#pragma unroll
    for (int off = 2; off < 64; off <<= 1)
#pragma unroll
        for (int k = 0; k < 8; ++k) acc[k] += __shfl_down(acc[k], off);
    if (lane < 2) {
        const float* rp = &resout[(long)d * 16 + t * 8];
        float4 r0 = *reinterpret_cast<const float4*>(rp);
        float4 r1 = *reinterpret_cast<const float4*>(rp + 4);
        float* op = &out[(long)d * 16 + t * 8];
        *reinterpret_cast<float4*>(op)     = make_float4(acc[0] + r0.x, acc[1] + r0.y, acc[2] + r0.z, acc[3] + r0.w);
        *reinterpret_cast<float4*>(op + 4) = make_float4(acc[4] + r1.x, acc[5] + r1.y, acc[6] + r1.z, acc[7] + r1.w);
    }
}

// ---------------- launch ----------------

extern "C" void kernel_launch(void* const* d_in, const int* in_sizes, int n_in,
                              void* d_out, int out_size, void* d_ws, size_t ws_size,
                              hipStream_t stream) {
    const float* x0   = (const float*)d_in[0];
    const float* x1   = (const float*)d_in[1];
    const float* x2   = (const float*)d_in[2];
    const float* fcw0 = (const float*)d_in[3];
    const float* fcb0 = (const float*)d_in[4];
    const float* fcw1 = (const float*)d_in[5];
    const float* fcb1 = (const float*)d_in[6];
    const float* fcw2 = (const float*)d_in[7];
    const float* fcb2 = (const float*)d_in[8];
    const float* W0   = (const float*)d_in[9];
    const float* We0  = (const float*)d_in[10];
    const float* eemb0= (const float*)d_in[11];
    const float* al0  = (const float*)d_in[12];
    const float* ar0  = (const float*)d_in[13];
    const float* ae0  = (const float*)d_in[14];
    const float* W1   = (const float*)d_in[15];
    const float* We1  = (const float*)d_in[16];
    const float* eemb1= (const float*)d_in[17];
    const float* al1  = (const float*)d_in[18];
    const float* ar1  = (const float*)d_in[19];
    const float* ae1  = (const float*)d_in[20];
    const float* resW1= (const float*)d_in[21];
    const float* W2   = (const float*)d_in[22];
    const float* We2  = (const float*)d_in[23];
    const float* eemb2= (const float*)d_in[24];
    const float* al2  = (const float*)d_in[25];
    const float* ar2  = (const float*)d_in[26];
    const float* ae2  = (const float*)d_in[27];
    const float* resW2= (const float*)d_in[28];
    const int* src    = (const int*)d_in[29];
    const int* dst    = (const int*)d_in[30];
    const int* etype  = (const int*)d_in[31];

    const int n0 = in_sizes[0] / 128;
    const int n1 = in_sizes[1] / 256;
    const int n2 = in_sizes[2] / 64;
    const int N  = n0 + n1 + n2;
    const int E  = in_sizes[29];

    char* w = (char*)d_ws;
    auto alloc = [&](size_t bytes) {
        char* p = w;
        w += (bytes + 255) & ~(size_t)255;
        return p;
    };
    int*    counts  = (int*)alloc((size_t)N * 4);
    int*    offsets = (int*)alloc((size_t)(N + 1) * 4);
    int*    cursor  = (int*)alloc((size_t)N * 4);
    int*    partial = (int*)alloc(1024 * 4);
    int*    se      = (int*)alloc((size_t)E * 4);
    ushort* h2res   = (ushort*)alloc((size_t)N * 256 * 2);
    ushort* a0b     = (ushort*)alloc((size_t)E * 8 * 2);
    // GEMM A-sources need >=128 rows of readable slack past the end (gload_lds tail):
    ushort* h0bf    = (ushort*)alloc((size_t)N * 64 * 2 + 128 * 256 * 2);
    ushort* featb   = (ushort*)alloc((size_t)N * 256 * 2);
    ushort* h1bf    = (ushort*)alloc((size_t)N * 256 * 2 + 128 * 256 * 2);
    ushort* h2bf    = (ushort*)alloc((size_t)N * 256 * 2 + 128 * 256 * 2);
    float*  el      = (float*)alloc((size_t)N * 8 * 4);
    float*  er      = (float*)alloc((size_t)N * 8 * 4);
    float*  etatt0  = (float*)alloc(64 * 4);
    float*  etatt1  = (float*)alloc(64 * 4);
    float*  etatt2  = (float*)alloc(64 * 4);
    ushort* Wt0     = (ushort*)alloc((size_t)256 * 64 * 2);
    ushort* Wt1     = (ushort*)alloc((size_t)256 * 256 * 2);
    ushort* WtR     = (ushort*)alloc((size_t)256 * 256 * 2);
    ushort* ft0     = (ushort*)alloc((size_t)64 * 128 * 2);
    ushort* ft1     = (ushort*)alloc((size_t)64 * 256 * 2);
    ushort* ft2     = (ushort*)alloc((size_t)64 * 64 * 2);
    ushort* Wt2R    = (ushort*)alloc((size_t)32 * 256 * 2);
    ushort* feat2b  = (ushort*)alloc((size_t)N * 16 * 2);
    float*  resout  = (float*)alloc((size_t)N * 16 * 4);
    float*  out     = (float*)d_out;

    const int TB = 256;
    int eb = (E + TB - 1) / TB;
    int nb1 = (N + 255) / 256;

    // ---- CSR build ----
    hipMemsetAsync(counts, 0, (size_t)N * 4, stream);
    hist_kernel<<<eb, TB, 0, stream>>>(dst, counts, E);
    scan_part<<<nb1, 256, 0, stream>>>(counts, offsets, partial, N);
    scan_top<<<1, 256, 0, stream>>>(partial, nb1);
    scan_add<<<nb1, 256, 0, stream>>>(offsets, cursor, partial, N);
    scatter_kernel<<<eb, TB, 0, stream>>>(src, dst, etype, cursor, se, E);

    // ---- prep (input-only deps) ----
    wprep<<<(184320 + TB - 1) / TB, TB, 0, stream>>>(W0, W1, resW1, fcw0, fcw1, fcw2,
                                                     W2, resW2,
                                                     Wt0, Wt1, WtR, ft0, ft1, ft2, Wt2R);
    etype_all<<<18, 512, 0, stream>>>(eemb0, We0, ae0, etatt0,
                                      eemb1, We1, ae1, etatt1,
                                      eemb2, We2, ae2, etatt2);

    // ---- input FC (bf16 MFMA, reg-staged f32 A, 3 segments) ----
    {
        int maxM = n0 > n1 ? n0 : n1;
        if (n2 > maxM) maxM = n2;
        dim3 g(1, (maxM + 127) / 128, 3);
        gemm_fc<<<g, TB, 0, stream>>>(x0, x1, x2, ft0, ft1, ft2, fcb0, fcb1, fcb2,
                                      h0bf, n0, n1, n2);
    }

    dim3 gg(256 / 128, (N + 127) / 128);

    // ---- layer 0 ----
    gemm_bf16<true><<<gg, TB, 0, stream>>>(h0bf, Wt0, featb, al0, ar0, el, er, N, 256, 64);
    fused_edge_h8<false, true, false><<<N, 64, 0, stream>>>(
        offsets, se, el, er, etatt0, featb, nullptr, a0b, nullptr, h1bf, N);

    // ---- layer 1 (dual-B GEMM: W1 -> featb (+el/er), resW1 -> h2res) ----
    gemm_dual<<<gg, TB, 0, stream>>>(h1bf, Wt1, WtR, featb, h2res, al1, ar1, el, er, N, 256, 256);
    fused_edge_h8<true, false, true><<<N, 64, 0, stream>>>(
        offsets, se, el, er, etatt1, featb, a0b, nullptr, h2res, h2bf, N);

    // ---- layer 2 (MFMA dual small matmul + fused edge with residual add) ----
    gemm_small<<<(N + 127) / 128, TB, 0, stream>>>(
        h2bf, Wt2R, feat2b, resout, al2, ar2, el, er, N);
    fused_edge_h1<<<N, 64, 0, stream>>>(offsets, se, el, er, etatt2, feat2b, resout, out, N);
}

// Round 17
// 389.510 us; speedup vs baseline: 1.1475x; 1.1475x over previous
//
#include <hip/hip_runtime.h>
#include <hip/hip_bf16.h>

#define ALPHA 0.05f
#define SLOPE 0.2f
#define LCAP 128

typedef __attribute__((ext_vector_type(8))) short short8v;
typedef __attribute__((ext_vector_type(8))) unsigned short ushort8v;
typedef __attribute__((ext_vector_type(4))) float floatx4;

__device__ inline ushort f2b(float f) {
    uint u = __float_as_uint(f);
    return (ushort)((u + 0x7fffu + ((u >> 16) & 1u)) >> 16);
}
__device__ inline float b2f(ushort b) { return __uint_as_float(((uint)b) << 16); }

// async global->LDS, 16B per lane (dest = wave-uniform base + lane*16)
__device__ inline void gload_lds16(const ushort* g, ushort* l) {
    __builtin_amdgcn_global_load_lds(
        (const __attribute__((address_space(1))) uint*)g,
        (__attribute__((address_space(3))) uint*)l, 16, 0, 0);
}

// ---------------- CSR build ----------------

__global__ void hist_kernel(const int* __restrict__ dst, int* __restrict__ counts, int E) {
    int e = blockIdx.x * blockDim.x + threadIdx.x;
    if (e < E) atomicAdd(&counts[dst[e]], 1);
}

__global__ __launch_bounds__(256) void scan_part(const int* __restrict__ counts,
                                                 int* __restrict__ offsets,
                                                 int* __restrict__ partial, int n) {
    __shared__ int sd[256];
    int i = blockIdx.x * 256 + threadIdx.x;
    int v = (i < n) ? counts[i] : 0;
    sd[threadIdx.x] = v;
    __syncthreads();
    for (int off = 1; off < 256; off <<= 1) {
        int t = (threadIdx.x >= off) ? sd[threadIdx.x - off] : 0;
        __syncthreads();
        sd[threadIdx.x] += t;
        __syncthreads();
    }
    if (i < n) offsets[i + 1] = sd[threadIdx.x];
    if (threadIdx.x == 255) partial[blockIdx.x] = sd[255];
}

__global__ __launch_bounds__(256) void scan_top(int* __restrict__ partial, int nb) {
    __shared__ int sd[256];
    int v = (threadIdx.x < nb) ? partial[threadIdx.x] : 0;
    sd[threadIdx.x] = v;
    __syncthreads();
    for (int off = 1; off < 256; off <<= 1) {
        int t = (threadIdx.x >= off) ? sd[threadIdx.x - off] : 0;
        __syncthreads();
        sd[threadIdx.x] += t;
        __syncthreads();
    }
    if (threadIdx.x < nb) partial[threadIdx.x] = sd[threadIdx.x];
}

__global__ __launch_bounds__(256) void scan_add(int* __restrict__ offsets,
                                                int* __restrict__ cursor,
                                                const int* __restrict__ partial, int n) {
    int i = blockIdx.x * 256 + threadIdx.x;
    if (i >= n) return;
    int add = (blockIdx.x > 0) ? partial[blockIdx.x - 1] : 0;
    int v = offsets[i + 1] + add;
    offsets[i + 1] = v;
    if (i + 1 < n) cursor[i + 1] = v;
    if (i == 0) { offsets[0] = 0; cursor[0] = 0; }
}

// pack (src<<3)|etype into one int per edge
__global__ void scatter_kernel(const int* __restrict__ src, const int* __restrict__ dst,
                               const int* __restrict__ et, int* __restrict__ cursor,
                               int* __restrict__ se, int E) {
    int e = blockIdx.x * blockDim.x + threadIdx.x;
    if (e >= E) return;
    int d = dst[e];
    int pos = atomicAdd(&cursor[d], 1);
    se[pos] = (src[e] << 3) | et[e];
}

// ---------------- weight prep (GAT + FC + layer-2 weights, one dispatch) ----------------

__global__ void wprep(const float* __restrict__ W0f, const float* __restrict__ W1f,
                      const float* __restrict__ WRf,
                      const float* __restrict__ fw0, const float* __restrict__ fw1,
                      const float* __restrict__ fw2,
                      const float* __restrict__ W2f, const float* __restrict__ WR2f,
                      ushort* __restrict__ Wt0, ushort* __restrict__ Wt1,
                      ushort* __restrict__ WtR,
                      ushort* __restrict__ ft0, ushort* __restrict__ ft1,
                      ushort* __restrict__ ft2, ushort* __restrict__ Wt2R) {
    int i = blockIdx.x * blockDim.x + threadIdx.x;
    if (i < 16384) {                                  // W0 [64][256] -> Wt0 [256][64]
        int k = i / 256, n = i % 256;
        Wt0[n * 64 + k] = f2b(W0f[i]);
    } else if (i < 16384 + 65536) {                   // W1 [256][256] -> Wt1
        int j = i - 16384;
        int k = j / 256, n = j % 256;
        Wt1[n * 256 + k] = f2b(W1f[j]);
    } else if (i < 16384 + 2 * 65536) {               // resW1 -> WtR
        int j = i - 16384 - 65536;
        int k = j / 256, n = j % 256;
        WtR[n * 256 + k] = f2b(WRf[j]);
    } else if (i < 147456 + 8192) {                   // fcw0 [128][64] -> ft0 [64][128]
        int j = i - 147456;
        int k = j / 64, n = j % 64;
        ft0[n * 128 + k] = f2b(fw0[j]);
    } else if (i < 147456 + 8192 + 16384) {           // fcw1 [256][64] -> ft1 [64][256]
        int j = i - 147456 - 8192;
        int k = j / 64, n = j % 64;
        ft1[n * 256 + k] = f2b(fw1[j]);
    } else if (i < 147456 + 8192 + 16384 + 4096) {    // fcw2 [64][64] -> ft2 [64][64]
        int j = i - 147456 - 8192 - 16384;
        int k = j / 64, n = j % 64;
        ft2[n * 64 + k] = f2b(fw2[j]);
    } else if (i < 176128 + 4096) {                   // W2 [256][16] -> Wt2R rows 0-15
        int j = i - 176128;
        int k = j / 16, n = j % 16;
        Wt2R[n * 256 + k] = f2b(W2f[j]);
    } else if (i < 176128 + 8192) {                   // resW2 [256][16] -> Wt2R rows 16-31
        int j = i - 176128 - 4096;
        int k = j / 16, n = j % 16;
        Wt2R[(16 + n) * 256 + k] = f2b(WR2f[j]);
    }
}

// ---------------- merged etype attention (3 layers, one dispatch) ----------------

__global__ __launch_bounds__(512) void etype_all(
    const float* __restrict__ eemb0, const float* __restrict__ We0, const float* __restrict__ ae0, float* __restrict__ out0,
    const float* __restrict__ eemb1, const float* __restrict__ We1, const float* __restrict__ ae1, float* __restrict__ out1,
    const float* __restrict__ eemb2, const float* __restrict__ We2, const float* __restrict__ ae2, float* __restrict__ out2) {
    int layer = blockIdx.x / 6, t = blockIdx.x % 6;
    const float *eemb, *We, *ae;
    float* out;
    int H;
    if (layer == 0)      { eemb = eemb0; We = We0; ae = ae0; out = out0; H = 8; }
    else if (layer == 1) { eemb = eemb1; We = We1; ae = ae1; out = out1; H = 8; }
    else                 { eemb = eemb2; We = We2; ae = ae2; out = out2; H = 1; }
    __shared__ float es[64];
    int j = threadIdx.x;
    if (j < 64) es[j] = eemb[t * 64 + j];
    __syncthreads();
    if (j >= H * 64) return;
    float wsum = 0.f;
#pragma unroll 8
    for (int k = 0; k < 64; ++k) wsum += es[k] * We[k * (H * 64) + j];
    float v = wsum * ae[j];
#pragma unroll
    for (int off = 32; off > 0; off >>= 1) v += __shfl_down(v, off, 64);
    if ((j & 63) == 0) out[t * H + (j >> 6)] = v;
}

// ---------------- bf16 MFMA GEMM (global_load_lds) + optional el/er epilogue ----------------

template<bool ATTN>
__global__ __launch_bounds__(256) void gemm_bf16(const ushort* __restrict__ A,
                                                 const ushort* __restrict__ Bt,
                                                 ushort* __restrict__ Cb,
                                                 const float* __restrict__ al,
                                                 const float* __restrict__ ar,
                                                 float* __restrict__ el,
                                                 float* __restrict__ er,
                                                 int M, int N, int K) {
    __shared__ ushort As[128 * 32];
    __shared__ ushort Bs[128 * 32];
    int bm = blockIdx.y * 128, bn = blockIdx.x * 128;
    int tid = threadIdx.x;
    int wave = tid >> 6, lane = tid & 63;
    int wm = (wave >> 1) * 64, wn = (wave & 1) * 64;
    int r = tid >> 2, c = (tid & 3) * 8;
    floatx4 acc[4][4] = {};
    for (int k0 = 0; k0 < K; k0 += 32) {
        gload_lds16(&A[(long)(bm + r) * K + k0 + c],       &As[(size_t)tid * 8]);
        gload_lds16(&A[(long)(bm + 64 + r) * K + k0 + c],  &As[(size_t)(256 + tid) * 8]);
        gload_lds16(&Bt[(long)(bn + r) * K + k0 + c],      &Bs[(size_t)tid * 8]);
        gload_lds16(&Bt[(long)(bn + 64 + r) * K + k0 + c], &Bs[(size_t)(256 + tid) * 8]);
        __syncthreads();
        int lr = lane & 15, lk = (lane >> 4) * 8;
        short8v af[4], bfr[4];
#pragma unroll
        for (int i = 0; i < 4; ++i)
            af[i] = *reinterpret_cast<const short8v*>(&As[(wm + i * 16 + lr) * 32 + lk]);
#pragma unroll
        for (int j = 0; j < 4; ++j)
            bfr[j] = *reinterpret_cast<const short8v*>(&Bs[(wn + j * 16 + lr) * 32 + lk]);
#pragma unroll
        for (int i = 0; i < 4; ++i)
#pragma unroll
            for (int j = 0; j < 4; ++j)
                acc[i][j] = __builtin_amdgcn_mfma_f32_16x16x32_bf16(af[i], bfr[j], acc[i][j], 0, 0, 0);
        __syncthreads();
    }
    int col = lane & 15, rbase = (lane >> 4) * 4;
#pragma unroll
    for (int i = 0; i < 4; ++i) {
#pragma unroll
        for (int rr = 0; rr < 4; ++rr) {
            int gm = bm + wm + i * 16 + rbase + rr;
            if (gm >= M) continue;
#pragma unroll
            for (int j = 0; j < 4; ++j) {
                int gn = bn + wn + j * 16 + col;
                Cb[(long)gm * N + gn] = f2b(acc[i][j][rr]);
            }
        }
    }
    if (ATTN) {
        int hA = (bn + wn) >> 5;
        float alv[4], arv[4];
#pragma unroll
        for (int j = 0; j < 4; ++j) {
            int h = hA + (j >> 1);
            int o = (j & 1) * 16 + col;
            alv[j] = al[h * 32 + o];
            arv[j] = ar[h * 32 + o];
        }
#pragma unroll
        for (int i = 0; i < 4; ++i) {
#pragma unroll
            for (int rr = 0; rr < 4; ++rr) {
                float slA = acc[i][0][rr] * alv[0] + acc[i][1][rr] * alv[1];
                float slB = acc[i][2][rr] * alv[2] + acc[i][3][rr] * alv[3];
                float srA = acc[i][0][rr] * arv[0] + acc[i][1][rr] * arv[1];
                float srB = acc[i][2][rr] * arv[2] + acc[i][3][rr] * arv[3];
#pragma unroll
                for (int off = 1; off < 16; off <<= 1) {
                    slA += __shfl_xor(slA, off, 64);
                    slB += __shfl_xor(slB, off, 64);
                    srA += __shfl_xor(srA, off, 64);
                    srB += __shfl_xor(srB, off, 64);
                }
                int gm = bm + wm + i * 16 + rbase + rr;
                if (col == 0 && gm < M) {
                    el[gm * 8 + hA]     = slA;
                    el[gm * 8 + hA + 1] = slB;
                    er[gm * 8 + hA]     = srA;
                    er[gm * 8 + hA + 1] = srB;
                }
            }
        }
    }
}

// ---------------- dual-B GEMM: C1 = A@B1^T (+el/er), C2 = A@B2^T ----------------

__global__ __launch_bounds__(256) void gemm_dual(const ushort* __restrict__ A,
                                                 const ushort* __restrict__ B1,
                                                 const ushort* __restrict__ B2,
                                                 ushort* __restrict__ C1,
                                                 ushort* __restrict__ C2,
                                                 const float* __restrict__ al,
                                                 const float* __restrict__ ar,
                                                 float* __restrict__ el,
                                                 float* __restrict__ er,
                                                 int M, int N, int K) {
    __shared__ ushort As[128 * 32];
    __shared__ ushort Bs1[128 * 32];
    __shared__ ushort Bs2[128 * 32];
    int bm = blockIdx.y * 128, bn = blockIdx.x * 128;
    int tid = threadIdx.x;
    int wave = tid >> 6, lane = tid & 63;
    int wm = (wave >> 1) * 64, wn = (wave & 1) * 64;
    int r = tid >> 2, c = (tid & 3) * 8;
    floatx4 acc1[4][4] = {};
    floatx4 acc2[4][4] = {};
    for (int k0 = 0; k0 < K; k0 += 32) {
        gload_lds16(&A[(long)(bm + r) * K + k0 + c],        &As[(size_t)tid * 8]);
        gload_lds16(&A[(long)(bm + 64 + r) * K + k0 + c],   &As[(size_t)(256 + tid) * 8]);
        gload_lds16(&B1[(long)(bn + r) * K + k0 + c],       &Bs1[(size_t)tid * 8]);
        gload_lds16(&B1[(long)(bn + 64 + r) * K + k0 + c],  &Bs1[(size_t)(256 + tid) * 8]);
        gload_lds16(&B2[(long)(bn + r) * K + k0 + c],       &Bs2[(size_t)tid * 8]);
        gload_lds16(&B2[(long)(bn + 64 + r) * K + k0 + c],  &Bs2[(size_t)(256 + tid) * 8]);
        __syncthreads();
        int lr = lane & 15, lk = (lane >> 4) * 8;
        short8v af[4], bfr[4];
#pragma unroll
        for (int i = 0; i < 4; ++i)
            af[i] = *reinterpret_cast<const short8v*>(&As[(wm + i * 16 + lr) * 32 + lk]);
#pragma unroll
        for (int j = 0; j < 4; ++j)
            bfr[j] = *reinterpret_cast<const short8v*>(&Bs1[(wn + j * 16 + lr) * 32 + lk]);
#pragma unroll
        for (int i = 0; i < 4; ++i)
#pragma unroll
            for (int j = 0; j < 4; ++j)
                acc1[i][j] = __builtin_amdgcn_mfma_f32_16x16x32_bf16(af[i], bfr[j], acc1[i][j], 0, 0, 0);
#pragma unroll
        for (int j = 0; j < 4; ++j)
            bfr[j] = *reinterpret_cast<const short8v*>(&Bs2[(wn + j * 16 + lr) * 32 + lk]);
#pragma unroll
        for (int i = 0; i < 4; ++i)
#pragma unroll
            for (int j = 0; j < 4; ++j)
                acc2[i][j] = __builtin_amdgcn_mfma_f32_16x16x32_bf16(af[i], bfr[j], acc2[i][j], 0, 0, 0);
        __syncthreads();
    }
    int col = lane & 15, rbase = (lane >> 4) * 4;
#pragma unroll
    for (int i = 0; i < 4; ++i) {
#pragma unroll
        for (int rr = 0; rr < 4; ++rr) {
            int gm = bm + wm + i * 16 + rbase + rr;
            if (gm >= M) continue;
#pragma unroll
            for (int j = 0; j < 4; ++j) {
                int gn = bn + wn + j * 16 + col;
                C1[(long)gm * N + gn] = f2b(acc1[i][j][rr]);
                C2[(long)gm * N + gn] = f2b(acc2[i][j][rr]);
            }
        }
    }
    int hA = (bn + wn) >> 5;
    float alv[4], arv[4];
#pragma unroll
    for (int j = 0; j < 4; ++j) {
        int h = hA + (j >> 1);
        int o = (j & 1) * 16 + col;
        alv[j] = al[h * 32 + o];
        arv[j] = ar[h * 32 + o];
    }
#pragma unroll
    for (int i = 0; i < 4; ++i) {
#pragma unroll
        for (int rr = 0; rr < 4; ++rr) {
            float slA = acc1[i][0][rr] * alv[0] + acc1[i][1][rr] * alv[1];
            float slB = acc1[i][2][rr] * alv[2] + acc1[i][3][rr] * alv[3];
            float srA = acc1[i][0][rr] * arv[0] + acc1[i][1][rr] * arv[1];
            float srB = acc1[i][2][rr] * arv[2] + acc1[i][3][rr] * arv[3];
#pragma unroll
            for (int off = 1; off < 16; off <<= 1) {
                slA += __shfl_xor(slA, off, 64);
                slB += __shfl_xor(slB, off, 64);
                srA += __shfl_xor(srA, off, 64);
                srB += __shfl_xor(srB, off, 64);
            }
            int gm = bm + wm + i * 16 + rbase + rr;
            if (col == 0 && gm < M) {
                el[gm * 8 + hA]     = slA;
                el[gm * 8 + hA + 1] = slB;
                er[gm * 8 + hA]     = srA;
                er[gm * 8 + hA + 1] = srB;
            }
        }
    }
}

// ---------------- input FC: f32 A reg-staged->bf16 LDS, B via gload_lds, bias epilogue ----------------

__global__ __launch_bounds__(256) void gemm_fc(const float* __restrict__ x0,
                                               const float* __restrict__ x1,
                                               const float* __restrict__ x2,
                                               const ushort* __restrict__ ft0,
                                               const ushort* __restrict__ ft1,
                                               const ushort* __restrict__ ft2,
                                               const float* __restrict__ b0,
                                               const float* __restrict__ b1,
                                               const float* __restrict__ b2,
                                               ushort* __restrict__ C,
                                               int n0, int n1, int n2) {
    int z = blockIdx.z;
    const float* A;
    const ushort* Bt;
    const float* bias;
    int M, K;
    long coff;
    if (z == 0)      { A = x0; Bt = ft0; bias = b0; M = n0; K = 128; coff = 0; }
    else if (z == 1) { A = x1; Bt = ft1; bias = b1; M = n1; K = 256; coff = (long)n0 * 64; }
    else             { A = x2; Bt = ft2; bias = b2; M = n2; K = 64;  coff = (long)(n0 + n1) * 64; }
    int bm = blockIdx.y * 128;
    if (bm >= M) return;
    __shared__ ushort As[128 * 32];
    __shared__ ushort Bs[64 * 32];
    int tid = threadIdx.x;
    int wave = tid >> 6, lane = tid & 63;
    int wm = (wave >> 1) * 64, wn = (wave & 1) * 32;
    int r = tid >> 2, c = (tid & 3) * 8;
    floatx4 acc[4][2] = {};
    for (int k0 = 0; k0 < K; k0 += 32) {
        {
            int gm0 = bm + r, gm1 = bm + 64 + r;
            ushort8v u0 = {0, 0, 0, 0, 0, 0, 0, 0};
            ushort8v u1 = {0, 0, 0, 0, 0, 0, 0, 0};
            if (gm0 < M) {
                float4 lo = *reinterpret_cast<const float4*>(&A[(long)gm0 * K + k0 + c]);
                float4 hi = *reinterpret_cast<const float4*>(&A[(long)gm0 * K + k0 + c + 4]);
                u0[0] = f2b(lo.x); u0[1] = f2b(lo.y); u0[2] = f2b(lo.z); u0[3] = f2b(lo.w);
                u0[4] = f2b(hi.x); u0[5] = f2b(hi.y); u0[6] = f2b(hi.z); u0[7] = f2b(hi.w);
            }
            if (gm1 < M) {
                float4 lo = *reinterpret_cast<const float4*>(&A[(long)gm1 * K + k0 + c]);
                float4 hi = *reinterpret_cast<const float4*>(&A[(long)gm1 * K + k0 + c + 4]);
                u1[0] = f2b(lo.x); u1[1] = f2b(lo.y); u1[2] = f2b(lo.z); u1[3] = f2b(lo.w);
                u1[4] = f2b(hi.x); u1[5] = f2b(hi.y); u1[6] = f2b(hi.z); u1[7] = f2b(hi.w);
            }
            *reinterpret_cast<ushort8v*>(&As[(size_t)tid * 8]) = u0;
            *reinterpret_cast<ushort8v*>(&As[(size_t)(256 + tid) * 8]) = u1;
        }
        gload_lds16(&Bt[(long)r * K + k0 + c], &Bs[(size_t)tid * 8]);
        __syncthreads();
        int lr = lane & 15, lk = (lane >> 4) * 8;
        short8v af[4], bfr[2];
#pragma unroll
        for (int i = 0; i < 4; ++i)
            af[i] = *reinterpret_cast<const short8v*>(&As[(wm + i * 16 + lr) * 32 + lk]);
#pragma unroll
        for (int j = 0; j < 2; ++j)
            bfr[j] = *reinterpret_cast<const short8v*>(&Bs[(wn + j * 16 + lr) * 32 + lk]);
#pragma unroll
        for (int i = 0; i < 4; ++i)
#pragma unroll
            for (int j = 0; j < 2; ++j)
                acc[i][j] = __builtin_amdgcn_mfma_f32_16x16x32_bf16(af[i], bfr[j], acc[i][j], 0, 0, 0);
        __syncthreads();
    }
    int col = lane & 15, rbase = (lane >> 4) * 4;
#pragma unroll
    for (int i = 0; i < 4; ++i) {
#pragma unroll
        for (int rr = 0; rr < 4; ++rr) {
            int gm = bm + wm + i * 16 + rbase + rr;
            if (gm >= M) continue;
#pragma unroll
            for (int j = 0; j < 2; ++j) {
                int gn = wn + j * 16 + col;
                C[coff + (long)gm * 64 + gn] = f2b(acc[i][j][rr] + bias[gn]);
            }
        }
    }
}

// ---------------- layer-2 MFMA: s1=A@W2 (->feat2b,el,er), s2=A@resW2 (->resout) ----------------

__global__ __launch_bounds__(256) void gemm_small(const ushort* __restrict__ A,
                                                  const ushort* __restrict__ Wt2R,
                                                  ushort* __restrict__ feat2b,
                                                  float* __restrict__ resout,
                                                  const float* __restrict__ al,
                                                  const float* __restrict__ ar,
                                                  float* __restrict__ el,
                                                  float* __restrict__ er, int M) {
    __shared__ ushort As[128 * 32];
    __shared__ ushort Bs[32 * 256];
    int tid = threadIdx.x;
    int wave = tid >> 6, lane = tid & 63;
    int bm = blockIdx.x * 128;
    for (int i = tid; i < 32 * 256 / 8; i += 256)
        *reinterpret_cast<ushort8v*>(&Bs[(size_t)i * 8]) =
            *reinterpret_cast<const ushort8v*>(&Wt2R[(size_t)i * 8]);
    __syncthreads();
    int r = tid >> 2, c = (tid & 3) * 8;
    floatx4 acc[2][2] = {};
    for (int k0 = 0; k0 < 256; k0 += 32) {
        gload_lds16(&A[(long)(bm + r) * 256 + k0 + c],      &As[(size_t)tid * 8]);
        gload_lds16(&A[(long)(bm + 64 + r) * 256 + k0 + c], &As[(size_t)(256 + tid) * 8]);
        __syncthreads();
        int lr = lane & 15, lk = (lane >> 4) * 8;
        short8v af[2], bfr[2];
#pragma unroll
        for (int i = 0; i < 2; ++i)
            af[i] = *reinterpret_cast<const short8v*>(&As[(wave * 32 + i * 16 + lr) * 32 + lk]);
#pragma unroll
        for (int j = 0; j < 2; ++j)
            bfr[j] = *reinterpret_cast<const short8v*>(&Bs[(j * 16 + lr) * 256 + k0 + lk]);
#pragma unroll
        for (int i = 0; i < 2; ++i)
#pragma unroll
            for (int j = 0; j < 2; ++j)
                acc[i][j] = __builtin_amdgcn_mfma_f32_16x16x32_bf16(af[i], bfr[j], acc[i][j], 0, 0, 0);
        __syncthreads();
    }
    int col = lane & 15, rbase = (lane >> 4) * 4;
    float alv = al[col], arv = ar[col];
#pragma unroll
    for (int i = 0; i < 2; ++i) {
#pragma unroll
        for (int rr = 0; rr < 4; ++rr) {
            int gm = bm + wave * 32 + i * 16 + rbase + rr;
            float s1 = acc[i][0][rr];
            float s2 = acc[i][1][rr];
            float sl = s1 * alv, sr = s1 * arv;
#pragma unroll
            for (int off = 1; off < 16; off <<= 1) {
                sl += __shfl_xor(sl, off, 64);
                sr += __shfl_xor(sr, off, 64);
            }
            if (gm < M) {
                feat2b[(long)gm * 16 + col] = f2b(s1);
                resout[(long)gm * 16 + col] = s2;
                if (col == 0) { el[gm] = sl; er[gm] = sr; }
            }
        }
    }
}

// ---------------- fused logits+softmax+aggregate, H=8, OUT=32, bf16 feat ----------------
// one block (64 threads = 1 wave) per dst node; se packed = (src<<3)|etype

template<bool BLEND, bool SAVE, bool RES>
__global__ __launch_bounds__(64) void fused_edge_h8(
    const int* __restrict__ offsets, const int* __restrict__ se,
    const float* __restrict__ el, const float* __restrict__ er,
    const float* __restrict__ etatt,
    const ushort* __restrict__ featb,
    const ushort* __restrict__ a0_in, ushort* __restrict__ a0_out,
    const ushort* __restrict__ resin, ushort* __restrict__ outb, int N) {
    int d = blockIdx.x;
    int lane = threadIdx.x;
    int lo = offsets[d], hi = offsets[d + 1];
    int deg = hi - lo;
    __shared__ float a_lds[LCAP][8];
    __shared__ int   s_lds[LCAP];
    __shared__ float er_s[8];
    __shared__ float m_s[8], inv_s[8];
    if (lane < 8) er_s[lane] = er[d * 8 + lane];
    __syncthreads();
    bool fast = (deg <= LCAP);
    int half = lane >> 5, t = lane & 31;
    int h8 = t >> 2;
    uint4 pf[4];
    int npf = 0;
    if (fast) {
        for (int i = lane; i < deg * 8; i += 64) {
            int p = i >> 3, h = i & 7;
            int v0 = se[lo + p];
            int s = v0 >> 3, tt = v0 & 7;
            if (h == 0) s_lds[p] = s;
            float v = el[s * 8 + h] + er_s[h] + etatt[tt * 8 + h];
            a_lds[p][h] = v > 0.f ? v : SLOPE * v;
        }
        __syncthreads();
        // prefetch first up-to-4 edges per half-wave; latency hides under softmax
#pragma unroll
        for (int u = 0; u < 4; ++u) {
            int p = half + 2 * u;
            if (p < deg) {
                pf[u] = *reinterpret_cast<const uint4*>(&featb[(long)s_lds[p] * 256 + t * 8]);
                npf = u + 1;
            }
        }
        {
            int g = lane >> 3, h = lane & 7;
            float m = -INFINITY;
            for (int p = g; p < deg; p += 8) m = fmaxf(m, a_lds[p][h]);
#pragma unroll
            for (int off = 8; off < 64; off <<= 1) m = fmaxf(m, __shfl_xor(m, off, 64));
            float ssum = 0.f;
            for (int p = g; p < deg; p += 8) ssum += __expf(a_lds[p][h] - m);
#pragma unroll
            for (int off = 8; off < 64; off <<= 1) ssum += __shfl_xor(ssum, off, 64);
            if (g == 0) {
                m_s[h] = m;
                inv_s[h] = ssum > 0.f ? 1.f / ssum : 0.f;
            }
        }
        __syncthreads();
        for (int i = lane; i < deg * 8; i += 64) {
            int p = i >> 3, h = i & 7;
            float a = __expf(a_lds[p][h] - m_s[h]) * inv_s[h];
            if (BLEND) a = a * (1.f - ALPHA) + b2f(a0_in[lo * 8 + i]) * ALPHA;
            a_lds[p][h] = a;
            if (SAVE) a0_out[lo * 8 + i] = f2b(a);
        }
        __syncthreads();
    } else {
        int g = lane >> 3, h = lane & 7;
        float m = -INFINITY;
        for (int p = g; p < deg; p += 8) {
            int v0 = se[lo + p];
            int s = v0 >> 3, tt = v0 & 7;
            float v = el[s * 8 + h] + er_s[h] + etatt[tt * 8 + h];
            v = v > 0.f ? v : SLOPE * v;
            m = fmaxf(m, v);
        }
#pragma unroll
        for (int off = 8; off < 64; off <<= 1) m = fmaxf(m, __shfl_xor(m, off, 64));
        float ssum = 0.f;
        for (int p = g; p < deg; p += 8) {
            int v0 = se[lo + p];
            int s = v0 >> 3, tt = v0 & 7;
            float v = el[s * 8 + h] + er_s[h] + etatt[tt * 8 + h];
            v = v > 0.f ? v : SLOPE * v;
            ssum += __expf(v - m);
        }
#pragma unroll
        for (int off = 8; off < 64; off <<= 1) ssum += __shfl_xor(ssum, off, 64);
        if (g == 0) {
            m_s[h] = m;
            inv_s[h] = ssum > 0.f ? 1.f / ssum : 0.f;
        }
        __syncthreads();
        if (SAVE) {
            for (int i = lane; i < deg * 8; i += 64) {
                int p = i >> 3, hh = i & 7;
                int v0 = se[lo + p];
                int s = v0 >> 3, tt = v0 & 7;
                float v = el[s * 8 + hh] + er_s[hh] + etatt[tt * 8 + hh];
                v = v > 0.f ? v : SLOPE * v;
                float a = __expf(v - m_s[hh]) * inv_s[hh];
                if (BLEND) a = a * (1.f - ALPHA) + b2f(a0_in[lo * 8 + i]) * ALPHA;
                a0_out[lo * 8 + i] = f2b(a);
            }
        }
    }
    // aggregation
    float acc[8];
#pragma unroll
    for (int k = 0; k < 8; ++k) acc[k] = 0.f;
    if (RES && half == 0) {
        uint4 rv = *reinterpret_cast<const uint4*>(&resin[(long)d * 256 + t * 8]);
        const uint* rp = reinterpret_cast<const uint*>(&rv);
#pragma unroll
        for (int q = 0; q < 4; ++q) {
            acc[2 * q]     = __uint_as_float(rp[q] << 16);
            acc[2 * q + 1] = __uint_as_float(rp[q] & 0xffff0000u);
        }
    }
    if (fast) {
        // consume prefetched edges
#pragma unroll
        for (int u = 0; u < 4; ++u) {
            if (u < npf) {
                float a = a_lds[half + 2 * u][h8];
                const uint* fp = reinterpret_cast<const uint*>(&pf[u]);
#pragma unroll
                for (int q = 0; q < 4; ++q) {
                    acc[2 * q]     += __uint_as_float(fp[q] << 16) * a;
                    acc[2 * q + 1] += __uint_as_float(fp[q] & 0xffff0000u) * a;
                }
            }
        }
        int p = half + 8;
        for (; p + 6 < deg; p += 8) {
            int s0 = s_lds[p],     s1 = s_lds[p + 2];
            int s2 = s_lds[p + 4], s3 = s_lds[p + 6];
            float a0 = a_lds[p][h8],     a1 = a_lds[p + 2][h8];
            float a2 = a_lds[p + 4][h8], a3 = a_lds[p + 6][h8];
            uint4 f0 = *reinterpret_cast<const uint4*>(&featb[(long)s0 * 256 + t * 8]);
            uint4 f1 = *reinterpret_cast<const uint4*>(&featb[(long)s1 * 256 + t * 8]);
            uint4 f2 = *reinterpret_cast<const uint4*>(&featb[(long)s2 * 256 + t * 8]);
            uint4 f3 = *reinterpret_cast<const uint4*>(&featb[(long)s3 * 256 + t * 8]);
            const uint* q0 = reinterpret_cast<const uint*>(&f0);
            const uint* q1 = reinterpret_cast<const uint*>(&f1);
            const uint* q2 = reinterpret_cast<const uint*>(&f2);
            const uint* q3 = reinterpret_cast<const uint*>(&f3);
#pragma unroll
            for (int q = 0; q < 4; ++q) {
                acc[2 * q] += __uint_as_float(q0[q] << 16) * a0
                            + __uint_as_float(q1[q] << 16) * a1
                            + __uint_as_float(q2[q] << 16) * a2
                            + __uint_as_float(q3[q] << 16) * a3;
                acc[2 * q + 1] += __uint_as_float(q0[q] & 0xffff0000u) * a0
                                + __uint_as_float(q1[q] & 0xffff0000u) * a1
                                + __uint_as_float(q2[q] & 0xffff0000u) * a2
                                + __uint_as_float(q3[q] & 0xffff0000u) * a3;
            }
        }
        for (; p < deg; p += 2) {
            int s = s_lds[p];
            float a = a_lds[p][h8];
            uint4 fv = *reinterpret_cast<const uint4*>(&featb[(long)s * 256 + t * 8]);
            const uint* fp = reinterpret_cast<const uint*>(&fv);
#pragma unroll
            for (int q = 0; q < 4; ++q) {
                uint u = fp[q];
                acc[2 * q]     += __uint_as_float(u << 16) * a;
                acc[2 * q + 1] += __uint_as_float(u & 0xffff0000u) * a;
            }
        }
    } else {
        for (int p = half; p < deg; p += 2) {
            int v0 = se[lo + p];
            int s = v0 >> 3, tt = v0 & 7;
            float v = el[s * 8 + h8] + er_s[h8] + etatt[tt * 8 + h8];
            v = v > 0.f ? v : SLOPE * v;
            float a = __expf(v - m_s[h8]) * inv_s[h8];
            if (BLEND) a = a * (1.f - ALPHA) + b2f(a0_in[(long)(lo + p) * 8 + h8]) * ALPHA;
            uint4 fv = *reinterpret_cast<const uint4*>(&featb[(long)s * 256 + t * 8]);
            const uint* fp = reinterpret_cast<const uint*>(&fv);
#pragma unroll
            for (int q = 0; q < 4; ++q) {
                uint u = fp[q];
                acc[2 * q]     += __uint_as_float(u << 16) * a;
                acc[2 * q + 1] += __uint_as_float(u & 0xffff0000u) * a;
            }
        }
    }
#pragma unroll
    for (int k = 0; k < 8; ++k) acc[k] += __shfl_down(acc[k], 32);
    if (half == 0) {
        ushort8v o;
#pragma unroll
        for (int k = 0; k < 8; ++k) {
            float v = acc[k];
            v = v > 0.f ? v : __expf(v) - 1.f;
            o[k] = f2b(v);
        }
        *reinterpret_cast<ushort8v*>(&outb[(long)d * 256 + t * 8]) = o;
    }
}

// ---------------- fused edge kernel, H=1, OUT=16, bf16 feat, + residual add ----------------

__global__ __launch_bounds__(64) void fused_edge_h1(
    const int* __restrict__ offsets, const int* __restrict__ se,
    const float* __restrict__ el, const float* __restrict__ er,
    const float* __restrict__ etatt,
    const ushort* __restrict__ featb2, const float* __restrict__ resout,
    float* __restrict__ out, int N) {
    int d = blockIdx.x;
    int lane = threadIdx.x;
    int lo = offsets[d], hi = offsets[d + 1];
    int deg = hi - lo;
    __shared__ float a_lds[512];
    float er_d = er[d];
    bool fast = (deg <= 512);
    float m = -INFINITY, inv = 0.f;
    if (fast) {
        for (int i = lane; i < deg; i += 64) {
            int v0 = se[lo + i];
            int s = v0 >> 3, t = v0 & 7;
            float v = el[s] + er_d + etatt[t];
            a_lds[i] = v > 0.f ? v : SLOPE * v;
        }
        __syncthreads();
        for (int i = lane; i < deg; i += 64) m = fmaxf(m, a_lds[i]);
#pragma unroll
        for (int off = 1; off < 64; off <<= 1) m = fmaxf(m, __shfl_xor(m, off, 64));
        float ssum = 0.f;
        for (int i = lane; i < deg; i += 64) ssum += __expf(a_lds[i] - m);
#pragma unroll
        for (int off = 1; off < 64; off <<= 1) ssum += __shfl_xor(ssum, off, 64);
        inv = ssum > 0.f ? 1.f / ssum : 0.f;
        for (int i = lane; i < deg; i += 64) a_lds[i] = __expf(a_lds[i] - m) * inv;
        __syncthreads();
    } else {
        for (int i = lane; i < deg; i += 64) {
            int v0 = se[lo + i];
            int s = v0 >> 3, t = v0 & 7;
            float v = el[s] + er_d + etatt[t];
            v = v > 0.f ? v : SLOPE * v;
            m = fmaxf(m, v);
        }
#pragma unroll
        for (int off = 1; off < 64; off <<= 1) m = fmaxf(m, __shfl_xor(m, off, 64));
        float ssum = 0.f;
        for (int i = lane; i < deg; i += 64) {
            int v0 = se[lo + i];
            int s = v0 >> 3, t = v0 & 7;
            float v = el[s] + er_d + etatt[t];
            v = v > 0.f ? v : SLOPE * v;
            ssum += __expf(v - m);
        }
#pragma unroll
        for (int off = 1; off < 64; off <<= 1) ssum += __shfl_xor(ssum, off, 64);
        inv = ssum > 0.f ? 1.f / ssum : 0.f;
    }
    int g = lane >> 1, t = lane & 1;       // 32 edge groups x 2 lanes (8 bf16 ch each)
    float acc[8];
#pragma unroll
    for (int k = 0; k < 8; ++k) acc[k] = 0.f;
    for (int p = g; p < deg; p += 32) {
        int v0 = se[lo + p];
        int s = v0 >> 3;
        float a;
        if (fast) a = a_lds[p];
        else {
            int tt = v0 & 7;
            float v = el[s] + er_d + etatt[tt];
            v = v > 0.f ? v : SLOPE * v;
            a = __expf(v - m) * inv;
        }
        uint4 fv = *reinterpret_cast<const uint4*>(&featb2[(long)s * 16 + t * 8]);
        const uint* fp = reinterpret_cast<const uint*>(&fv);
#pragma unroll
        for (int q = 0; q < 4; ++q) {
            acc[2 * q]     += __uint_as_float(fp[q] << 16) * a;
            acc[2 * q + 1] += __uint_as_float(fp[q] & 0xffff0000u) * a;
        }
    }
#pragma unroll
    for (int off = 2; off < 64; off <<= 1)
#pragma unroll
        for (int k = 0; k < 8; ++k) acc[k] += __shfl_down(acc[k], off);
    if (lane < 2) {
        const float* rp = &resout[(long)d * 16 + t * 8];
        float4 r0 = *reinterpret_cast<const float4*>(rp);
        float4 r1 = *reinterpret_cast<const float4*>(rp + 4);
        float* op = &out[(long)d * 16 + t * 8];
        *reinterpret_cast<float4*>(op)     = make_float4(acc[0] + r0.x, acc[1] + r0.y, acc[2] + r0.z, acc[3] + r0.w);
        *reinterpret_cast<float4*>(op + 4) = make_float4(acc[4] + r1.x, acc[5] + r1.y, acc[6] + r1.z, acc[7] + r1.w);
    }
}

// ---------------- launch ----------------

extern "C" void kernel_launch(void* const* d_in, const int* in_sizes, int n_in,
                              void* d_out, int out_size, void* d_ws, size_t ws_size,
                              hipStream_t stream) {
    const float* x0   = (const float*)d_in[0];
    const float* x1   = (const float*)d_in[1];
    const float* x2   = (const float*)d_in[2];
    const float* fcw0 = (const float*)d_in[3];
    const float* fcb0 = (const float*)d_in[4];
    const float* fcw1 = (const float*)d_in[5];
    const float* fcb1 = (const float*)d_in[6];
    const float* fcw2 = (const float*)d_in[7];
    const float* fcb2 = (const float*)d_in[8];
    const float* W0   = (const float*)d_in[9];
    const float* We0  = (const float*)d_in[10];
    const float* eemb0= (const float*)d_in[11];
    const float* al0  = (const float*)d_in[12];
    const float* ar0  = (const float*)d_in[13];
    const float* ae0  = (const float*)d_in[14];
    const float* W1   = (const float*)d_in[15];
    const float* We1  = (const float*)d_in[16];
    const float* eemb1= (const float*)d_in[17];
    const float* al1  = (const float*)d_in[18];
    const float* ar1  = (const float*)d_in[19];
    const float* ae1  = (const float*)d_in[20];
    const float* resW1= (const float*)d_in[21];
    const float* W2   = (const float*)d_in[22];
    const float* We2  = (const float*)d_in[23];
    const float* eemb2= (const float*)d_in[24];
    const float* al2  = (const float*)d_in[25];
    const float* ar2  = (const float*)d_in[26];
    const float* ae2  = (const float*)d_in[27];
    const float* resW2= (const float*)d_in[28];
    const int* src    = (const int*)d_in[29];
    const int* dst    = (const int*)d_in[30];
    const int* etype  = (const int*)d_in[31];

    const int n0 = in_sizes[0] / 128;
    const int n1 = in_sizes[1] / 256;
    const int n2 = in_sizes[2] / 64;
    const int N  = n0 + n1 + n2;
    const int E  = in_sizes[29];

    char* w = (char*)d_ws;
    auto alloc = [&](size_t bytes) {
        char* p = w;
        w += (bytes + 255) & ~(size_t)255;
        return p;
    };
    int*    counts  = (int*)alloc((size_t)N * 4);
    int*    offsets = (int*)alloc((size_t)(N + 1) * 4);
    int*    cursor  = (int*)alloc((size_t)N * 4);
    int*    partial = (int*)alloc(1024 * 4);
    int*    se      = (int*)alloc((size_t)E * 4);
    ushort* h2res   = (ushort*)alloc((size_t)N * 256 * 2);
    ushort* a0b     = (ushort*)alloc((size_t)E * 8 * 2);
    // GEMM A-sources need >=128 rows of readable slack past the end (gload_lds tail):
    ushort* h0bf    = (ushort*)alloc((size_t)N * 64 * 2 + 128 * 256 * 2);
    ushort* featb   = (ushort*)alloc((size_t)N * 256 * 2);
    ushort* h1bf    = (ushort*)alloc((size_t)N * 256 * 2 + 128 * 256 * 2);
    ushort* h2bf    = (ushort*)alloc((size_t)N * 256 * 2 + 128 * 256 * 2);
    float*  el      = (float*)alloc((size_t)N * 8 * 4);
    float*  er      = (float*)alloc((size_t)N * 8 * 4);
    float*  etatt0  = (float*)alloc(64 * 4);
    float*  etatt1  = (float*)alloc(64 * 4);
    float*  etatt2  = (float*)alloc(64 * 4);
    ushort* Wt0     = (ushort*)alloc((size_t)256 * 64 * 2);
    ushort* Wt1     = (ushort*)alloc((size_t)256 * 256 * 2);
    ushort* WtR     = (ushort*)alloc((size_t)256 * 256 * 2);
    ushort* ft0     = (ushort*)alloc((size_t)64 * 128 * 2);
    ushort* ft1     = (ushort*)alloc((size_t)64 * 256 * 2);
    ushort* ft2     = (ushort*)alloc((size_t)64 * 64 * 2);
    ushort* Wt2R    = (ushort*)alloc((size_t)32 * 256 * 2);
    ushort* feat2b  = (ushort*)alloc((size_t)N * 16 * 2);
    float*  resout  = (float*)alloc((size_t)N * 16 * 4);
    float*  out     = (float*)d_out;

    const int TB = 256;
    int eb = (E + TB - 1) / TB;
    int nb1 = (N + 255) / 256;

    // ---- CSR build ----
    hipMemsetAsync(counts, 0, (size_t)N * 4, stream);
    hist_kernel<<<eb, TB, 0, stream>>>(dst, counts, E);
    scan_part<<<nb1, 256, 0, stream>>>(counts, offsets, partial, N);
    scan_top<<<1, 256, 0, stream>>>(partial, nb1);
    scan_add<<<nb1, 256, 0, stream>>>(offsets, cursor, partial, N);
    scatter_kernel<<<eb, TB, 0, stream>>>(src, dst, etype, cursor, se, E);

    // ---- prep (input-only deps) ----
    wprep<<<(184320 + TB - 1) / TB, TB, 0, stream>>>(W0, W1, resW1, fcw0, fcw1, fcw2,
                                                     W2, resW2,
                                                     Wt0, Wt1, WtR, ft0, ft1, ft2, Wt2R);
    etype_all<<<18, 512, 0, stream>>>(eemb0, We0, ae0, etatt0,
                                      eemb1, We1, ae1, etatt1,
                                      eemb2, We2, ae2, etatt2);

    // ---- input FC (bf16 MFMA, reg-staged f32 A, 3 segments) ----
    {
        int maxM = n0 > n1 ? n0 : n1;
        if (n2 > maxM) maxM = n2;
        dim3 g(1, (maxM + 127) / 128, 3);
        gemm_fc<<<g, TB, 0, stream>>>(x0, x1, x2, ft0, ft1, ft2, fcb0, fcb1, fcb2,
                                      h0bf, n0, n1, n2);
    }

    dim3 gg(256 / 128, (N + 127) / 128);

    // ---- layer 0 ----
    gemm_bf16<true><<<gg, TB, 0, stream>>>(h0bf, Wt0, featb, al0, ar0, el, er, N, 256, 64);
    fused_edge_h8<false, true, false><<<N, 64, 0, stream>>>(
        offsets, se, el, er, etatt0, featb, nullptr, a0b, nullptr, h1bf, N);

    // ---- layer 1 (dual-B GEMM: W1 -> featb (+el/er), resW1 -> h2res) ----
    gemm_dual<<<gg, TB, 0, stream>>>(h1bf, Wt1, WtR, featb, h2res, al1, ar1, el, er, N, 256, 256);
    fused_edge_h8<true, false, true><<<N, 64, 0, stream>>>(
        offsets, se, el, er, etatt1, featb, a0b, nullptr, h2res, h2bf, N);

    // ---- layer 2 (MFMA dual small matmul + fused edge with residual add) ----
    gemm_small<<<(N + 127) / 128, TB, 0, stream>>>(
        h2bf, Wt2R, feat2b, resout, al2, ar2, el, er, N);
    fused_edge_h1<<<N, 64, 0, stream>>>(offsets, se, el, er, etatt2, feat2b, resout, out, N);
}